// Round 9
// baseline (1625.084 us; speedup 1.0000x reference)
//
#include <hip/hip_runtime.h>

#define MTOT 65536   // B*V
#define KTOT 1024    // F
#define NTOT 1024    // U

#define BM 256
#define BN 256
#define BK 32
#define NSTEP (KTOT / BK)   // 32

typedef __attribute__((ext_vector_type(4))) unsigned int u32x4;
typedef __attribute__((ext_vector_type(4))) float f32x4;
typedef __attribute__((ext_vector_type(8))) __bf16 bf16x8;
typedef __attribute__((ext_vector_type(4))) unsigned short u16x4;

static __device__ __forceinline__ unsigned short f2bf(float f) {
    unsigned int u = __float_as_uint(f);
    u += 0x7fffu + ((u >> 16) & 1u);   // round-to-nearest-even
    return (unsigned short)(u >> 16);
}

#define GLOAD16(g, l)                                                              \
    __builtin_amdgcn_global_load_lds(                                              \
        (const __attribute__((address_space(1))) void*)(g),                        \
        (__attribute__((address_space(3))) void*)(l), 16, 0, 0)

// ---- prep: valid + fp32->bf16 feature convert + invalid-row passthrough ----
// (round-5/7 verified; runs near the HBM ceiling)
__global__ __launch_bounds__(256) void prep_kernel(const int* __restrict__ adj,
                                                   const float* __restrict__ feat,
                                                   unsigned short* __restrict__ abf,
                                                   unsigned char* __restrict__ valid,
                                                   float* __restrict__ out) {
    const int row  = blockIdx.x * 4 + (threadIdx.x >> 6);
    const int lane = threadIdx.x & 63;
    const int2 a2  = reinterpret_cast<const int2*>(adj)[(size_t)row * 64 + lane];
    const bool anyv = __any((a2.x >= 0) || (a2.y >= 0)) != 0;

    const f32x4* frow = reinterpret_cast<const f32x4*>(feat + (size_t)row * KTOT);
    u16x4*       brow = reinterpret_cast<u16x4*>(abf + (size_t)row * KTOT);
    f32x4*       orow = reinterpret_cast<f32x4*>(out + (size_t)row * NTOT);
    if (anyv) {
#pragma unroll
        for (int i = 0; i < 4; ++i) {
            const f32x4 v = frow[lane + 64 * i];
            u16x4 b;
            b.x = f2bf(v[0]); b.y = f2bf(v[1]); b.z = f2bf(v[2]); b.w = f2bf(v[3]);
            brow[lane + 64 * i] = b;
        }
    } else {
#pragma unroll
        for (int i = 0; i < 4; ++i)
            orow[lane + 64 * i] = frow[lane + 64 * i];   // K==N passthrough
    }
    if (lane == 0) valid[row] = anyv ? 1 : 0;
}

// ---- prep 2: kT[n][k] = bf16(kern[k][n]) ----
__global__ __launch_bounds__(256) void transposeB_kernel(const float* __restrict__ kern,
                                                         unsigned short* __restrict__ kT) {
    __shared__ float tile[32][33];
    const int bx = blockIdx.x & 31;
    const int by = blockIdx.x >> 5;
    const int tx = threadIdx.x & 31;
    const int ty = threadIdx.x >> 5;
#pragma unroll
    for (int r = 0; r < 4; ++r)
        tile[ty + r * 8][tx] = kern[(size_t)(by * 32 + ty + r * 8) * NTOT + bx * 32 + tx];
    __syncthreads();
#pragma unroll
    for (int r = 0; r < 4; ++r)
        kT[(size_t)(bx * 32 + ty + r * 8) * KTOT + by * 32 + tx] = f2bf(tile[tx][ty + r * 8]);
}

// ---- main GEMM: 256x256, BK=32, 16 waves (4Mx4N, 64x64 each), DOUBLE buffer ----
// m97-style loop: stage tile t+1 (global_load_lds), MFMA on tile t, __syncthreads
// (full vmcnt/lgkm drain). 64 KiB LDS -> 2 blocks/CU co-resident (32 waves/CU):
// the sibling block's waves cover the per-step drain stall (TLP, m97 precedent).
// No setprio (m190: hurts lockstep GEMM). Addressing identical to round-7
// (involution chunk swizzle, measured 0 bank conflicts).
__global__ __launch_bounds__(1024, 8) void gemm_kernel(const unsigned short* __restrict__ A,
                                                       const unsigned short* __restrict__ Bt,
                                                       const float* __restrict__ bias,
                                                       const unsigned char* __restrict__ valid,
                                                       float* __restrict__ out) {
    __shared__ __align__(16) unsigned short Asm[2 * 8192];   // 2 bufs x 256x32 bf16
    __shared__ __align__(16) unsigned short Bsm[2 * 8192];

    const int tid  = threadIdx.x;
    const int lane = tid & 63;
    const int wv   = tid >> 6;     // 0..15
    const int wm   = wv >> 2;      // wave M quarter (rows wm*64..+64)
    const int wn   = wv & 3;       // wave N quarter (cols wn*64..+64)

    // bijective XCD swizzle (nwg = 1024, divisible by 8)
    const int cpx = (int)gridDim.x >> 3;
    const int swz = ((int)blockIdx.x & 7) * cpx + ((int)blockIdx.x >> 3);
    const int bm  = swz >> 2;      // 0..255
    const int bn  = swz & 3;       // 0..3
    const size_t m0 = (size_t)bm * BM;
    const int    n0 = bn * BN;

    // staging: thread covers tile row tid>>2 (0..255), PHYS 16B chunk tid&3;
    // source logical chunk = phys ^ ((row>>1)&3)  (involution, verified r2/r7)
    const int srow   = tid >> 2;
    const int lch    = (tid & 3) ^ ((tid >> 3) & 3);
    const size_t s_goff = (size_t)srow * KTOT + lch * 8;   // ushort units
    const int    s_loff = wv << 9;                         // wave-uniform LDS base (ush)

    const unsigned short* Agl = A  + m0 * (size_t)KTOT + s_goff;
    const unsigned short* Bgl = Bt + (size_t)n0 * KTOT + s_goff;

#define STAGE(b, kt) do {                                                          \
        GLOAD16(Agl + (kt) * BK, &Asm[(b) * 8192 + s_loff]);                       \
        GLOAD16(Bgl + (kt) * BK, &Bsm[(b) * 8192 + s_loff]);                       \
    } while (0)

    // fragment read addressing: lane wants logical chunk g4 of row (…+lr)
    // -> phys = g4 ^ ((lr>>1)&3); 2-way bank aliasing max (free)
    const int lr  = lane & 15;
    const int g4  = lane >> 4;
    const int rsw = (g4 ^ ((lr >> 1) & 3)) << 3;
    int aridx[4], bridx[4];
#pragma unroll
    for (int m = 0; m < 4; ++m)
        aridx[m] = (wm * 64 + m * 16 + lr) * BK + rsw;
#pragma unroll
    for (int n = 0; n < 4; ++n)
        bridx[n] = (wn * 64 + n * 16 + lr) * BK + rsw;

    f32x4 acc[4][4];
#pragma unroll
    for (int m = 0; m < 4; ++m)
#pragma unroll
        for (int n = 0; n < 4; ++n)
            acc[m][n] = {0.0f, 0.0f, 0.0f, 0.0f};

    // prologue: tile 0 -> buf 0, full drain
    STAGE(0, 0);
    __syncthreads();

#pragma unroll
    for (int t = 0; t < NSTEP; ++t) {
        if (t + 1 < NSTEP) STAGE((t + 1) & 1, t + 1);   // async loads overlap MFMA
        const int b = t & 1;
        bf16x8 af[4], bfr[4];
#pragma unroll
        for (int n = 0; n < 4; ++n)
            bfr[n] = __builtin_bit_cast(bf16x8, *reinterpret_cast<const u32x4*>(&Bsm[b * 8192 + bridx[n]]));
#pragma unroll
        for (int m = 0; m < 4; ++m)
            af[m] = __builtin_bit_cast(bf16x8, *reinterpret_cast<const u32x4*>(&Asm[b * 8192 + aridx[m]]));
#pragma unroll
        for (int m = 0; m < 4; ++m)
#pragma unroll
            for (int n = 0; n < 4; ++n)
                acc[m][n] = __builtin_amdgcn_mfma_f32_16x16x32_bf16(af[m], bfr[n], acc[m][n], 0, 0, 0);
        if (t < NSTEP - 1) __syncthreads();   // drains vmcnt (next tile ready) + WAR
    }

    // epilogue: C/D layout col=lane&15, row=(lane>>4)*4+q ; valid rows only
    // (invalid rows already written by prep passthrough)
    float bv[4];
#pragma unroll
    for (int n = 0; n < 4; ++n)
        bv[n] = bias[n0 + wn * 64 + n * 16 + lr];

#pragma unroll
    for (int m = 0; m < 4; ++m) {
#pragma unroll
        for (int q = 0; q < 4; ++q) {
            const size_t row = m0 + wm * 64 + m * 16 + g4 * 4 + q;
            if (valid[row]) {
                const size_t ro = row * NTOT + n0 + wn * 64 + lr;
#pragma unroll
                for (int n = 0; n < 4; ++n)
                    out[ro + n * 16] = fmaxf(acc[m][n][q] + bv[n], 0.0f);
            }
        }
    }
#undef STAGE
}

extern "C" void kernel_launch(void* const* d_in, const int* in_sizes, int n_in,
                              void* d_out, int out_size, void* d_ws, size_t ws_size,
                              hipStream_t stream) {
    const int*   adj  = (const int*)d_in[0];
    const float* feat = (const float*)d_in[1];
    const float* kern = (const float*)d_in[2];
    const float* bias = (const float*)d_in[3];
    float* out = (float*)d_out;

    unsigned short* kT    = (unsigned short*)d_ws;                             // 2 MB
    unsigned char*  valid = (unsigned char*)d_ws + 2 * 1024 * 1024;            // 64 KB
    unsigned short* abf   = (unsigned short*)((char*)d_ws + 2 * 1024 * 1024 + 65536);

    transposeB_kernel<<<(KTOT / 32) * (NTOT / 32), 256, 0, stream>>>(kern, kT);
    prep_kernel<<<MTOT / 4, 256, 0, stream>>>(adj, feat, abf, valid, out);
    gemm_kernel<<<(MTOT / BM) * (NTOT / BN), 1024, 0, stream>>>(abf, kT, bias, valid, out);
}

// Round 10
// 287.091 us; speedup vs baseline: 5.6605x; 5.6605x over previous
//
#include <hip/hip_runtime.h>

#define MTOT 65536   // B*V
#define KTOT 1024    // F
#define NTOT 1024    // U

#define BM 256
#define BN 128
#define BK 32
#define NSTEP (KTOT / BK)   // 32

typedef __attribute__((ext_vector_type(4))) unsigned int u32x4;
typedef __attribute__((ext_vector_type(4))) float f32x4;
typedef __attribute__((ext_vector_type(8))) __bf16 bf16x8;
typedef __attribute__((ext_vector_type(4))) unsigned short u16x4;

static __device__ __forceinline__ unsigned short f2bf(float f) {
    unsigned int u = __float_as_uint(f);
    u += 0x7fffu + ((u >> 16) & 1u);   // round-to-nearest-even
    return (unsigned short)(u >> 16);
}

#define GLOAD16(g, l)                                                              \
    __builtin_amdgcn_global_load_lds(                                              \
        (const __attribute__((address_space(1))) void*)(g),                        \
        (__attribute__((address_space(3))) void*)(l), 16, 0, 0)

#define VMCNT(n) asm volatile("s_waitcnt vmcnt(" #n ")" ::: "memory")
#define CFENCE   asm volatile("" ::: "memory")
#define BAR()    __builtin_amdgcn_s_barrier()

// ---- prep: valid + fp32->bf16 feature convert + invalid-row passthrough ----
// (round-5/7 verified; runs near the HBM ceiling)
__global__ __launch_bounds__(256) void prep_kernel(const int* __restrict__ adj,
                                                   const float* __restrict__ feat,
                                                   unsigned short* __restrict__ abf,
                                                   unsigned char* __restrict__ valid,
                                                   float* __restrict__ out) {
    const int row  = blockIdx.x * 4 + (threadIdx.x >> 6);
    const int lane = threadIdx.x & 63;
    const int2 a2  = reinterpret_cast<const int2*>(adj)[(size_t)row * 64 + lane];
    const bool anyv = __any((a2.x >= 0) || (a2.y >= 0)) != 0;

    const f32x4* frow = reinterpret_cast<const f32x4*>(feat + (size_t)row * KTOT);
    u16x4*       brow = reinterpret_cast<u16x4*>(abf + (size_t)row * KTOT);
    f32x4*       orow = reinterpret_cast<f32x4*>(out + (size_t)row * NTOT);
    if (anyv) {
#pragma unroll
        for (int i = 0; i < 4; ++i) {
            const f32x4 v = frow[lane + 64 * i];
            u16x4 b;
            b.x = f2bf(v[0]); b.y = f2bf(v[1]); b.z = f2bf(v[2]); b.w = f2bf(v[3]);
            brow[lane + 64 * i] = b;
        }
    } else {
#pragma unroll
        for (int i = 0; i < 4; ++i)
            orow[lane + 64 * i] = frow[lane + 64 * i];   // K==N passthrough
    }
    if (lane == 0) valid[row] = anyv ? 1 : 0;
}

// ---- prep 2: kT[n][k] = bf16(kern[k][n]) ----
__global__ __launch_bounds__(256) void transposeB_kernel(const float* __restrict__ kern,
                                                         unsigned short* __restrict__ kT) {
    __shared__ float tile[32][33];
    const int bx = blockIdx.x & 31;
    const int by = blockIdx.x >> 5;
    const int tx = threadIdx.x & 31;
    const int ty = threadIdx.x >> 5;
#pragma unroll
    for (int r = 0; r < 4; ++r)
        tile[ty + r * 8][tx] = kern[(size_t)(by * 32 + ty + r * 8) * NTOT + bx * 32 + tx];
    __syncthreads();
#pragma unroll
    for (int r = 0; r < 4; ++r)
        kT[(size_t)(bx * 32 + ty + r * 8) * KTOT + by * 32 + tx] = f2bf(tile[tx][ty + r * 8]);
}

// ---- main GEMM: 256x128 tile, BK=32, 8 waves (4Mx2N, 64x64 each), TRIPLE buffer
// 72 KiB LDS -> 2 blocks/CU co-resident (16 waves/CU, the 128-reg ceiling), but in
// TWO barrier-independent blocks: when one block drains at its barrier, the other's
// 8 waves keep issuing (m97 TLP mechanism). Counted vmcnt depth-2 prefetch:
// stage tile t+2 at step t (3 gloads: A h0, A h1, B); vmcnt(3) at step end confirms
// tile t+1 (issued 2 steps ago, ~2 steps of latency cover), leaves newest stage in
// flight — never 0 until tail. WAR: buf (t+2)%3 was read at step t-1, one barrier
// ago. Addressing = verified involution swizzle (r2/r7, 0 conflicts). No setprio.
__global__ __launch_bounds__(512, 4) void gemm_kernel(const unsigned short* __restrict__ A,
                                                      const unsigned short* __restrict__ Bt,
                                                      const float* __restrict__ bias,
                                                      const unsigned char* __restrict__ valid,
                                                      float* __restrict__ out) {
    __shared__ __align__(16) unsigned short Asm[3 * 8192];   // 3 bufs x 256x32 bf16 (16 KB)
    __shared__ __align__(16) unsigned short Bsm[3 * 4096];   // 3 bufs x 128x32 bf16 (8 KB)

    const int tid  = threadIdx.x;
    const int lane = tid & 63;
    const int wv   = tid >> 6;     // 0..7
    const int wm   = wv >> 1;      // wave M quarter (rows wm*64..+64)
    const int wn   = wv & 1;       // wave N half   (cols wn*64..+64)

    // bijective XCD swizzle (nwg = 2048, divisible by 8); 8 bn-blocks per bm
    // stay on one XCD -> A-panel L2 locality
    const int cpx = (int)gridDim.x >> 3;
    const int swz = ((int)blockIdx.x & 7) * cpx + ((int)blockIdx.x >> 3);
    const int bm  = swz >> 3;      // 0..255
    const int bn  = swz & 7;       // 0..7
    const size_t m0 = (size_t)bm * BM;
    const int    n0 = bn * BN;

    // staging: thread covers row tid>>2 (0..127; +128 for A h1), PHYS chunk tid&3;
    // source logical chunk = phys ^ ((row>>1)&3) (involution; row+128 preserves it)
    const int srow = tid >> 2;
    const int lch  = (tid & 3) ^ ((tid >> 3) & 3);
    const size_t s_goff = (size_t)srow * KTOT + lch * 8;   // ushort units
    const int    s_loff = wv << 9;                         // wave-uniform LDS base (ush)

    const unsigned short* Agl = A  + m0 * (size_t)KTOT + s_goff;
    const unsigned short* Bgl = Bt + (size_t)n0 * KTOT + s_goff;

#define STAGE(b, kt) do {                                                          \
        GLOAD16(Agl + (kt) * BK, &Asm[(b) * 8192 + s_loff]);                       \
        GLOAD16(Agl + (size_t)128 * KTOT + (kt) * BK, &Asm[(b) * 8192 + 4096 + s_loff]); \
        GLOAD16(Bgl + (kt) * BK, &Bsm[(b) * 4096 + s_loff]);                       \
    } while (0)

    // fragment read addressing: phys = logical(g4) ^ ((lr>>1)&3); 2-way max (free)
    const int lr  = lane & 15;
    const int g4  = lane >> 4;
    const int rsw = (g4 ^ ((lr >> 1) & 3)) << 3;
    int aridx[4], bridx[4];
#pragma unroll
    for (int m = 0; m < 4; ++m)
        aridx[m] = (wm * 64 + m * 16 + lr) * BK + rsw;   // rows 0..255 -> [0,8192) ush
#pragma unroll
    for (int n = 0; n < 4; ++n)
        bridx[n] = (wn * 64 + n * 16 + lr) * BK + rsw;   // rows 0..127 -> [0,4096) ush

    f32x4 acc[4][4];
#pragma unroll
    for (int m = 0; m < 4; ++m)
#pragma unroll
        for (int n = 0; n < 4; ++n)
            acc[m][n] = {0.0f, 0.0f, 0.0f, 0.0f};

    // prologue: tiles 0,1 staged (6 loads); confirm tile 0 (oldest 3)
    STAGE(0, 0);
    STAGE(1, 1);
    VMCNT(3);
    BAR(); CFENCE;

#pragma unroll
    for (int t = 0; t < NSTEP; ++t) {
        if (t + 2 < NSTEP) STAGE((t + 2) % 3, t + 2);
        const int b = t % 3;
        bf16x8 af[4], bfr[4];
#pragma unroll
        for (int n = 0; n < 4; ++n)
            bfr[n] = __builtin_bit_cast(bf16x8, *reinterpret_cast<const u32x4*>(&Bsm[b * 4096 + bridx[n]]));
#pragma unroll
        for (int m = 0; m < 4; ++m)
            af[m] = __builtin_bit_cast(bf16x8, *reinterpret_cast<const u32x4*>(&Asm[b * 8192 + aridx[m]]));
#pragma unroll
        for (int m = 0; m < 4; ++m)
#pragma unroll
            for (int n = 0; n < 4; ++n)
                acc[m][n] = __builtin_amdgcn_mfma_f32_16x16x32_bf16(af[m], bfr[n], acc[m][n], 0, 0, 0);
        if (t < NSTEP - 2)       VMCNT(3);   // confirm tile t+1, leave newest stage in flight
        else if (t == NSTEP - 2) VMCNT(0);   // tail: confirm last tile
        if (t < NSTEP - 1) { BAR(); CFENCE; }
    }

    // epilogue: C/D layout col=lane&15, row=(lane>>4)*4+q ; valid rows only
    // (invalid rows already written by prep passthrough)
    float bv[4];
#pragma unroll
    for (int n = 0; n < 4; ++n)
        bv[n] = bias[n0 + wn * 64 + n * 16 + lr];

#pragma unroll
    for (int m = 0; m < 4; ++m) {
#pragma unroll
        for (int q = 0; q < 4; ++q) {
            const size_t row = m0 + wm * 64 + m * 16 + g4 * 4 + q;
            if (valid[row]) {
                const size_t ro = row * NTOT + n0 + wn * 64 + lr;
#pragma unroll
                for (int n = 0; n < 4; ++n)
                    out[ro + n * 16] = fmaxf(acc[m][n][q] + bv[n], 0.0f);
            }
        }
    }
#undef STAGE
}

extern "C" void kernel_launch(void* const* d_in, const int* in_sizes, int n_in,
                              void* d_out, int out_size, void* d_ws, size_t ws_size,
                              hipStream_t stream) {
    const int*   adj  = (const int*)d_in[0];
    const float* feat = (const float*)d_in[1];
    const float* kern = (const float*)d_in[2];
    const float* bias = (const float*)d_in[3];
    float* out = (float*)d_out;

    unsigned short* kT    = (unsigned short*)d_ws;                             // 2 MB
    unsigned char*  valid = (unsigned char*)d_ws + 2 * 1024 * 1024;            // 64 KB
    unsigned short* abf   = (unsigned short*)((char*)d_ws + 2 * 1024 * 1024 + 65536);

    transposeB_kernel<<<(KTOT / 32) * (NTOT / 32), 256, 0, stream>>>(kern, kT);
    prep_kernel<<<MTOT / 4, 256, 0, stream>>>(adj, feat, abf, valid, out);
    gemm_kernel<<<(MTOT / BM) * (NTOT / BN), 512, 0, stream>>>(abf, kT, bias, valid, out);
}

// Round 11
// 261.115 us; speedup vs baseline: 6.2236x; 1.0995x over previous
//
#include <hip/hip_runtime.h>

#define MTOT 65536   // B*V
#define KTOT 1024    // F
#define NTOT 1024    // U

#define BM 256
#define BN 256
#define BK 32
#define NSTEP (KTOT / BK)   // 32

typedef __attribute__((ext_vector_type(4))) unsigned int u32x4;
typedef __attribute__((ext_vector_type(4))) float f32x4;
typedef __attribute__((ext_vector_type(8))) __bf16 bf16x8;
typedef __attribute__((ext_vector_type(4))) unsigned short u16x4;

static __device__ __forceinline__ unsigned short f2bf(float f) {
    unsigned int u = __float_as_uint(f);
    u += 0x7fffu + ((u >> 16) & 1u);   // round-to-nearest-even
    return (unsigned short)(u >> 16);
}

#define GLOAD16(g, l)                                                              \
    __builtin_amdgcn_global_load_lds(                                              \
        (const __attribute__((address_space(1))) void*)(g),                        \
        (__attribute__((address_space(3))) void*)(l), 16, 0, 0)

#define VMCNT(n) asm volatile("s_waitcnt vmcnt(" #n ")" ::: "memory")
#define CFENCE   asm volatile("" ::: "memory")
#define BAR()    __builtin_amdgcn_s_barrier()

// ---- prep: valid + fp32->bf16 feature convert + invalid-row passthrough ----
// (round-5/7 verified; runs near the HBM ceiling)
__global__ __launch_bounds__(256) void prep_kernel(const int* __restrict__ adj,
                                                   const float* __restrict__ feat,
                                                   unsigned short* __restrict__ abf,
                                                   unsigned char* __restrict__ valid,
                                                   float* __restrict__ out) {
    const int row  = blockIdx.x * 4 + (threadIdx.x >> 6);
    const int lane = threadIdx.x & 63;
    const int2 a2  = reinterpret_cast<const int2*>(adj)[(size_t)row * 64 + lane];
    const bool anyv = __any((a2.x >= 0) || (a2.y >= 0)) != 0;

    const f32x4* frow = reinterpret_cast<const f32x4*>(feat + (size_t)row * KTOT);
    u16x4*       brow = reinterpret_cast<u16x4*>(abf + (size_t)row * KTOT);
    f32x4*       orow = reinterpret_cast<f32x4*>(out + (size_t)row * NTOT);
    if (anyv) {
#pragma unroll
        for (int i = 0; i < 4; ++i) {
            const f32x4 v = frow[lane + 64 * i];
            u16x4 b;
            b.x = f2bf(v[0]); b.y = f2bf(v[1]); b.z = f2bf(v[2]); b.w = f2bf(v[3]);
            brow[lane + 64 * i] = b;
        }
    } else {
#pragma unroll
        for (int i = 0; i < 4; ++i)
            orow[lane + 64 * i] = frow[lane + 64 * i];   // K==N passthrough
    }
    if (lane == 0) valid[row] = anyv ? 1 : 0;
}

// ---- prep 2: kT[n][k] = bf16(kern[k][n]) ----
__global__ __launch_bounds__(256) void transposeB_kernel(const float* __restrict__ kern,
                                                         unsigned short* __restrict__ kT) {
    __shared__ float tile[32][33];
    const int bx = blockIdx.x & 31;
    const int by = blockIdx.x >> 5;
    const int tx = threadIdx.x & 31;
    const int ty = threadIdx.x >> 5;
#pragma unroll
    for (int r = 0; r < 4; ++r)
        tile[ty + r * 8][tx] = kern[(size_t)(by * 32 + ty + r * 8) * NTOT + bx * 32 + tx];
    __syncthreads();
#pragma unroll
    for (int r = 0; r < 4; ++r)
        kT[(size_t)(bx * 32 + ty + r * 8) * KTOT + by * 32 + tx] = f2bf(tile[tx][ty + r * 8]);
}

// ---- main GEMM: 256x256 tile, BK=32, 16 waves (4M x 4N, 64x64 each),
//      quad-buffered counted-vmcnt pipeline (round-3/7 verified logic),
//      round-2 verified involution swizzle. 128 KiB LDS, 4 waves/SIMD.
// Pipeline: phase t reads buf[t&3]; stages tile t+3 into buf[(t+3)&3]
// (= buffer read at phase t-1; WAR-safe: those ds_reads drained before the
// t-1 end barrier via MFMA data deps). vmcnt(4) leaves tiles t+2,t+3 (2 loads
// each) in flight across the barrier; confirms tile t+1 issued 3 phases ago.
__global__ __launch_bounds__(1024, 4) void gemm_kernel(const unsigned short* __restrict__ A,
                                                       const unsigned short* __restrict__ Bt,
                                                       const float* __restrict__ bias,
                                                       const unsigned char* __restrict__ valid,
                                                       float* __restrict__ out) {
    __shared__ __align__(16) unsigned short Asm[4 * 8192];   // 4 bufs x 256x32 bf16
    __shared__ __align__(16) unsigned short Bsm[4 * 8192];

    const int tid  = threadIdx.x;
    const int lane = tid & 63;
    const int wv   = tid >> 6;     // 0..15
    const int wm   = wv >> 2;      // wave M quarter (rows wm*64..+64)
    const int wn   = wv & 3;       // wave N quarter (cols wn*64..+64)

    // bijective XCD swizzle (nwg = 1024, divisible by 8)
    const int cpx = (int)gridDim.x >> 3;
    const int swz = ((int)blockIdx.x & 7) * cpx + ((int)blockIdx.x >> 3);
    const int bm  = swz >> 2;      // 0..255
    const int bn  = swz & 3;       // 0..3
    const size_t m0 = (size_t)bm * BM;
    const int    n0 = bn * BN;

    // staging: thread covers tile row tid>>2 (0..255), PHYS 16B chunk tid&3;
    // source logical chunk = phys ^ ((row>>1)&3)  (involution, r2-verified)
    const int srow   = tid >> 2;
    const int lch    = (tid & 3) ^ ((tid >> 3) & 3);
    const size_t s_goff = (size_t)srow * KTOT + lch * 8;   // ushort units
    const int    s_loff = wv << 9;                         // wave-uniform LDS base (ush)

    const unsigned short* Agl = A  + m0 * (size_t)KTOT + s_goff;
    const unsigned short* Bgl = Bt + (size_t)n0 * KTOT + s_goff;

#define STAGE(b, kt) do {                                                          \
        GLOAD16(Agl + (kt) * BK, &Asm[(b) * 8192 + s_loff]);                       \
        GLOAD16(Bgl + (kt) * BK, &Bsm[(b) * 8192 + s_loff]);                       \
    } while (0)

    // fragment read addressing: lane wants logical chunk g4 of row (…+lr)
    // -> phys = g4 ^ ((lr>>1)&3); bank-quad = 4*(row&1) + phys -> 2-way max (free)
    const int lr  = lane & 15;
    const int g4  = lane >> 4;
    const int rsw = (g4 ^ ((lr >> 1) & 3)) << 3;
    int aridx[4], bridx[4];
#pragma unroll
    for (int m = 0; m < 4; ++m)
        aridx[m] = (wm * 64 + m * 16 + lr) * BK + rsw;
#pragma unroll
    for (int n = 0; n < 4; ++n)
        bridx[n] = (wn * 64 + n * 16 + lr) * BK + rsw;

    f32x4 acc[4][4];
#pragma unroll
    for (int m = 0; m < 4; ++m)
#pragma unroll
        for (int n = 0; n < 4; ++n)
            acc[m][n] = {0.0f, 0.0f, 0.0f, 0.0f};

    // prologue: 3 tiles in flight (6 loads); confirm tile 0 (oldest 2)
    STAGE(0, 0);
    STAGE(1, 1);
    STAGE(2, 2);
    VMCNT(4);
    BAR(); CFENCE;

#pragma unroll
    for (int t = 0; t < NSTEP; ++t) {
        if (t + 3 < NSTEP) STAGE((t + 3) & 3, t + 3);
        const int b = t & 3;
        bf16x8 af[4], bf[4];
#pragma unroll
        for (int n = 0; n < 4; ++n)
            bf[n] = __builtin_bit_cast(bf16x8, *reinterpret_cast<const u32x4*>(&Bsm[b * 8192 + bridx[n]]));
#pragma unroll
        for (int m = 0; m < 4; ++m)
            af[m] = __builtin_bit_cast(bf16x8, *reinterpret_cast<const u32x4*>(&Asm[b * 8192 + aridx[m]]));
        __builtin_amdgcn_s_setprio(1);
#pragma unroll
        for (int m = 0; m < 4; ++m)
#pragma unroll
            for (int n = 0; n < 4; ++n)
                acc[m][n] = __builtin_amdgcn_mfma_f32_16x16x32_bf16(af[m], bf[n], acc[m][n], 0, 0, 0);
        __builtin_amdgcn_s_setprio(0);
        if (t < NSTEP - 3)       VMCNT(4);
        else if (t == NSTEP - 3) VMCNT(2);
        else if (t == NSTEP - 2) VMCNT(0);
        if (t < NSTEP - 1) { BAR(); CFENCE; }
    }

    // epilogue: C/D layout col=lane&15, row=(lane>>4)*4+q ; valid rows only
    // (invalid rows already written by prep passthrough)
    float bv[4];
#pragma unroll
    for (int n = 0; n < 4; ++n)
        bv[n] = bias[n0 + wn * 64 + n * 16 + lr];

#pragma unroll
    for (int m = 0; m < 4; ++m) {
#pragma unroll
        for (int q = 0; q < 4; ++q) {
            const size_t row = m0 + wm * 64 + m * 16 + g4 * 4 + q;
            if (valid[row]) {
                const size_t ro = row * NTOT + n0 + wn * 64 + lr;
#pragma unroll
                for (int n = 0; n < 4; ++n)
                    out[ro + n * 16] = fmaxf(acc[m][n][q] + bv[n], 0.0f);
            }
        }
    }
#undef STAGE
}

extern "C" void kernel_launch(void* const* d_in, const int* in_sizes, int n_in,
                              void* d_out, int out_size, void* d_ws, size_t ws_size,
                              hipStream_t stream) {
    const int*   adj  = (const int*)d_in[0];
    const float* feat = (const float*)d_in[1];
    const float* kern = (const float*)d_in[2];
    const float* bias = (const float*)d_in[3];
    float* out = (float*)d_out;

    unsigned short* kT    = (unsigned short*)d_ws;                             // 2 MB
    unsigned char*  valid = (unsigned char*)d_ws + 2 * 1024 * 1024;            // 64 KB
    unsigned short* abf   = (unsigned short*)((char*)d_ws + 2 * 1024 * 1024 + 65536);

    transposeB_kernel<<<(KTOT / 32) * (NTOT / 32), 256, 0, stream>>>(kern, kT);
    prep_kernel<<<MTOT / 4, 256, 0, stream>>>(adj, feat, abf, valid, out);
    gemm_kernel<<<(MTOT / BM) * (NTOT / BN), 1024, 0, stream>>>(abf, kT, bias, valid, out);
}